// Round 1
// baseline (320.639 us; speedup 1.0000x reference)
//
#include <hip/hip_runtime.h>

#define GYD 512
#define GXD 512
#define HD 256
#define WD 256
#define BD 8
#define NSAMP 100000
#define JD 7

__device__ __forceinline__ int brev9(int i) {
    return (int)(__brev((unsigned)i) >> 23);
}

// In-LDS 512-point radix-2 DIT FFT (input already stored bit-reversed).
// 256 threads, each does one butterfly per stage, 9 stages.
__device__ __forceinline__ void fft512(float* re, float* im, int t) {
    #pragma unroll
    for (int s = 1; s <= 9; ++s) {
        const int len = 1 << s;
        const int half = len >> 1;
        const int off = t & (half - 1);
        const int blk = t >> (s - 1);
        const int p = blk * len + off;
        const int q = p + half;
        float sn, cs;
        sincospif(-2.0f * (float)off / (float)len, &sn, &cs);
        __syncthreads();
        const float ur = re[p], ui = im[p];
        const float ar = re[q], ai = im[q];
        const float vr = ar * cs - ai * sn;
        const float vi = ar * sn + ai * cs;
        re[p] = ur + vr; im[p] = ui + vi;
        re[q] = ur - vr; im[q] = ui - vi;
    }
    __syncthreads();
}

// Kernel A: apodization + zero-padded row FFT. One block per (b, y).
__global__ __launch_bounds__(256) void rowfft_kernel(
    const float* __restrict__ xr, const float* __restrict__ xi,
    const float* __restrict__ sc_y, const float* __restrict__ sc_x,
    float2* __restrict__ G1)
{
    __shared__ float re[512];
    __shared__ float im[512];
    const int t = threadIdx.x;
    const int by = blockIdx.x;       // b*256 + y
    const int b = by >> 8;
    const int y = by & 255;
    const float s = sc_y[y] * sc_x[t];
    const int base = b * (HD * WD) + y * WD;
    const float vr = xr[base + t] * s;
    const float vi = xi[base + t] * s;
    const int p0 = brev9(t);
    re[p0] = vr; im[p0] = vi;
    const int p1 = brev9(t + 256);   // zero-padded half
    re[p1] = 0.0f; im[p1] = 0.0f;
    fft512(re, im, t);
    float2* out = G1 + (size_t)b * (HD * GXD) + (size_t)y * GXD;
    out[t]       = make_float2(re[t],       im[t]);
    out[t + 256] = make_float2(re[t + 256], im[t + 256]);
}

// Kernel B: zero-padded column FFT + ortho scale. One block per (b, kx).
__global__ __launch_bounds__(256) void colfft_kernel(
    const float2* __restrict__ G1, float2* __restrict__ ghat)
{
    __shared__ float re[512];
    __shared__ float im[512];
    const int t = threadIdx.x;
    const int bk = blockIdx.x;       // b*512 + kx
    const int b = bk >> 9;
    const int kx = bk & 511;
    const float2 v = G1[(size_t)b * (HD * GXD) + (size_t)t * GXD + kx];
    const int p0 = brev9(t);
    re[p0] = v.x; im[p0] = v.y;
    const int p1 = brev9(t + 256);   // rows 256..511 are zero
    re[p1] = 0.0f; im[p1] = 0.0f;
    fft512(re, im, t);
    const float scale = 1.0f / 512.0f;   // fft2 norm="ortho": 1/sqrt(512*512)
    float2* out = ghat + (size_t)b * (GYD * GXD) + kx;
    out[(size_t)t * GXD]         = make_float2(re[t] * scale,       im[t] * scale);
    out[(size_t)(t + 256) * GXD] = make_float2(re[t + 256] * scale, im[t + 256] * scale);
}

// Kernel C: 7x7 KB gather for all 8 batches per sample + phase.
__global__ __launch_bounds__(256) void gather_kernel(
    const float2* __restrict__ ghat,
    const float* __restrict__ wy, const float* __restrict__ wx,
    const float* __restrict__ phr, const float* __restrict__ phi,
    const int* __restrict__ iy, const int* __restrict__ ix,
    float2* __restrict__ out)
{
    const int n = blockIdx.x * 256 + threadIdx.x;
    if (n >= NSAMP) return;

    int iyl[JD], ixl[JD];
    float wyl[JD], wxl[JD];
    #pragma unroll
    for (int j = 0; j < JD; ++j) {
        iyl[j] = iy[n * JD + j];
        ixl[j] = ix[n * JD + j];
        wyl[j] = wy[n * JD + j];
        wxl[j] = wx[n * JD + j];
    }

    float accr[BD] = {0,0,0,0,0,0,0,0};
    float acci[BD] = {0,0,0,0,0,0,0,0};

    for (int j = 0; j < JD; ++j) {
        const int rowoff = iyl[j] * GXD;
        #pragma unroll
        for (int k = 0; k < JD; ++k) {
            const float w = wyl[j] * wxl[k];
            const int lin = rowoff + ixl[k];
            #pragma unroll
            for (int b = 0; b < BD; ++b) {
                const float2 g = ghat[(size_t)b * (GYD * GXD) + lin];
                accr[b] += g.x * w;
                acci[b] += g.y * w;
            }
        }
    }

    const float pr = phr[n], pi = phi[n];
    #pragma unroll
    for (int b = 0; b < BD; ++b) {
        const float outr = accr[b] * pr - acci[b] * pi;
        const float outi = accr[b] * pi + acci[b] * pr;
        out[(size_t)b * NSAMP + n] = make_float2(outr, outi);
    }
}

extern "C" void kernel_launch(void* const* d_in, const int* in_sizes, int n_in,
                              void* d_out, int out_size, void* d_ws, size_t ws_size,
                              hipStream_t stream) {
    const float* xr   = (const float*)d_in[0];
    const float* xi   = (const float*)d_in[1];
    const float* sc_y = (const float*)d_in[2];
    const float* sc_x = (const float*)d_in[3];
    const float* wy   = (const float*)d_in[4];
    const float* wx   = (const float*)d_in[5];
    const float* phr  = (const float*)d_in[6];
    const float* phi  = (const float*)d_in[7];
    const int*   iy   = (const int*)d_in[8];
    const int*   ix   = (const int*)d_in[9];

    // Workspace layout: G1 (8 MB) | ghat (16 MB)
    float2* G1   = (float2*)d_ws;
    float2* ghat = (float2*)((char*)d_ws + (size_t)BD * HD * GXD * sizeof(float2));

    rowfft_kernel<<<BD * HD, 256, 0, stream>>>(xr, xi, sc_y, sc_x, G1);
    colfft_kernel<<<BD * GXD, 256, 0, stream>>>(G1, ghat);
    gather_kernel<<<(NSAMP + 255) / 256, 256, 0, stream>>>(
        ghat, wy, wx, phr, phi, iy, ix, (float2*)d_out);
}

// Round 2
// 202.475 us; speedup vs baseline: 1.5836x; 1.5836x over previous
//
#include <hip/hip_runtime.h>

#define GYD 512
#define GXD 512
#define HD 256
#define WD 256
#define BD 8
#define NSAMP 100000
#define JD 7
#define NC 16           // columns per col-FFT tile
#define NCP 17          // padded LDS stride (breaks bank conflicts)

__device__ __forceinline__ int brev9(int i) {
    return (int)(__brev((unsigned)i) >> 23);
}

// In-LDS 512-point radix-2 DIT FFT (input already stored bit-reversed).
// 256 threads, each does one butterfly per stage, 9 stages.
__device__ __forceinline__ void fft512(float* re, float* im, int t) {
    #pragma unroll
    for (int s = 1; s <= 9; ++s) {
        const int len = 1 << s;
        const int half = len >> 1;
        const int off = t & (half - 1);
        const int blk = t >> (s - 1);
        const int p = blk * len + off;
        const int q = p + half;
        float sn, cs;
        sincospif(-2.0f * (float)off / (float)len, &sn, &cs);
        __syncthreads();
        const float ur = re[p], ui = im[p];
        const float ar = re[q], ai = im[q];
        const float vr = ar * cs - ai * sn;
        const float vi = ar * sn + ai * cs;
        re[p] = ur + vr; im[p] = ui + vi;
        re[q] = ur - vr; im[q] = ui - vi;
    }
    __syncthreads();
}

// Kernel A: apodization + zero-padded row FFT. One block per (b, y).
__global__ __launch_bounds__(256) void rowfft_kernel(
    const float* __restrict__ xr, const float* __restrict__ xi,
    const float* __restrict__ sc_y, const float* __restrict__ sc_x,
    float2* __restrict__ G1)
{
    __shared__ float re[512];
    __shared__ float im[512];
    const int t = threadIdx.x;
    const int by = blockIdx.x;       // b*256 + y
    const int b = by >> 8;
    const int y = by & 255;
    const float s = sc_y[y] * sc_x[t];
    const int base = b * (HD * WD) + y * WD;
    const float vr = xr[base + t] * s;
    const float vi = xi[base + t] * s;
    const int p0 = brev9(t);
    re[p0] = vr; im[p0] = vi;
    const int p1 = brev9(t + 256);   // zero-padded half
    re[p1] = 0.0f; im[p1] = 0.0f;
    fft512(re, im, t);
    float2* out = G1 + (size_t)b * (HD * GXD) + (size_t)y * GXD;
    out[t]       = make_float2(re[t],       im[t]);
    out[t + 256] = make_float2(re[t + 256], im[t + 256]);
}

// Kernel B: LDS-tiled zero-padded column FFT + ortho scale.
// One block per (b, 16-column tile): grid = 8 * 32 = 256 blocks.
// Coalesced loads (16 float2 = 128 B per row segment), 16 FFTs in LDS.
__global__ __launch_bounds__(256) void colfft_kernel(
    const float2* __restrict__ G1, float2* __restrict__ ghat)
{
    __shared__ float re[512 * NCP];
    __shared__ float im[512 * NCP];
    const int t = threadIdx.x;
    const int blk = blockIdx.x;           // b*32 + tile
    const int b = blk >> 5;
    const int kx0 = (blk & 31) * NC;

    // Load valid rows 0..255 bit-reversed; zero rows 256..511.
    const float2* src = G1 + (size_t)b * (HD * GXD) + kx0;
    for (int i = t; i < 256 * NC; i += 256) {
        const int y = i >> 4;
        const int c = i & 15;
        const float2 v = src[(size_t)y * GXD + c];
        const int p = brev9(y);
        re[p * NCP + c] = v.x;
        im[p * NCP + c] = v.y;
        const int p2 = brev9(y + 256);
        re[p2 * NCP + c] = 0.0f;
        im[p2 * NCP + c] = 0.0f;
    }
    __syncthreads();

    // 16 FFTs of length 512. Thread t: column c = t&15, sub-index tt = t>>4.
    // Per stage: 256 butterflies per FFT; each thread does 16 of them.
    const int c = t & 15;
    const int tt = t >> 4;
    #pragma unroll
    for (int s = 1; s <= 9; ++s) {
        const int len = 1 << s;
        const int half = len >> 1;
        #pragma unroll
        for (int k = 0; k < 16; ++k) {
            const int m = tt * 16 + k;           // butterfly index 0..255
            const int off = m & (half - 1);
            const int bi = m >> (s - 1);
            const int p = (bi * len + off) * NCP + c;
            const int q = p + half * NCP;
            float sn, cs;
            sincospif(-2.0f * (float)off / (float)len, &sn, &cs);
            const float ur = re[p], ui = im[p];
            const float ar = re[q], ai = im[q];
            const float vr = ar * cs - ai * sn;
            const float vi = ar * sn + ai * cs;
            re[p] = ur + vr; im[p] = ui + vi;
            re[q] = ur - vr; im[q] = ui - vi;
        }
        __syncthreads();
    }

    // Coalesced write-back with ortho scale.
    const float scale = 1.0f / 512.0f;   // 1/sqrt(512*512)
    float2* dst = ghat + (size_t)b * (GYD * GXD) + kx0;
    for (int i = t; i < 512 * NC; i += 256) {
        const int y = i >> 4;
        const int cc = i & 15;
        dst[(size_t)y * GXD + cc] =
            make_float2(re[y * NCP + cc] * scale, im[y * NCP + cc] * scale);
    }
}

// Kernel C: 7x7 KB gather, batch-per-XCD.
// b = blockIdx % 8 -> all blocks of batch b land on one XCD (SPX round-robin),
// so the 2 MB per-batch grid fits that XCD's 4 MB L2.
__global__ __launch_bounds__(256) void gather_kernel(
    const float2* __restrict__ ghat,
    const float* __restrict__ wy, const float* __restrict__ wx,
    const float* __restrict__ phr, const float* __restrict__ phi,
    const int* __restrict__ iy, const int* __restrict__ ix,
    float2* __restrict__ out)
{
    const int b = blockIdx.x & 7;
    const int chunk = blockIdx.x >> 3;
    const int n = chunk * 256 + threadIdx.x;
    if (n >= NSAMP) return;

    int iyl[JD], ixl[JD];
    float wyl[JD], wxl[JD];
    #pragma unroll
    for (int j = 0; j < JD; ++j) {
        iyl[j] = iy[n * JD + j];
        ixl[j] = ix[n * JD + j];
        wyl[j] = wy[n * JD + j];
        wxl[j] = wx[n * JD + j];
    }

    const float2* __restrict__ g = ghat + (size_t)b * (GYD * GXD);
    float ar = 0.0f, ai = 0.0f;
    #pragma unroll
    for (int j = 0; j < JD; ++j) {
        const int rowoff = iyl[j] * GXD;
        #pragma unroll
        for (int k = 0; k < JD; ++k) {
            const float w = wyl[j] * wxl[k];
            const float2 v = g[rowoff + ixl[k]];
            ar += v.x * w;
            ai += v.y * w;
        }
    }

    const float pr = phr[n], pi = phi[n];
    out[(size_t)b * NSAMP + n] = make_float2(ar * pr - ai * pi,
                                             ar * pi + ai * pr);
}

extern "C" void kernel_launch(void* const* d_in, const int* in_sizes, int n_in,
                              void* d_out, int out_size, void* d_ws, size_t ws_size,
                              hipStream_t stream) {
    const float* xr   = (const float*)d_in[0];
    const float* xi   = (const float*)d_in[1];
    const float* sc_y = (const float*)d_in[2];
    const float* sc_x = (const float*)d_in[3];
    const float* wy   = (const float*)d_in[4];
    const float* wx   = (const float*)d_in[5];
    const float* phr  = (const float*)d_in[6];
    const float* phi  = (const float*)d_in[7];
    const int*   iy   = (const int*)d_in[8];
    const int*   ix   = (const int*)d_in[9];

    // Workspace layout: G1 (8 MB) | ghat (16 MB)
    float2* G1   = (float2*)d_ws;
    float2* ghat = (float2*)((char*)d_ws + (size_t)BD * HD * GXD * sizeof(float2));

    rowfft_kernel<<<BD * HD, 256, 0, stream>>>(xr, xi, sc_y, sc_x, G1);
    colfft_kernel<<<BD * (GXD / NC), 256, 0, stream>>>(G1, ghat);

    const int chunks = (NSAMP + 255) / 256;
    gather_kernel<<<chunks * BD, 256, 0, stream>>>(
        ghat, wy, wx, phr, phi, iy, ix, (float2*)d_out);
}

// Round 3
// 166.401 us; speedup vs baseline: 1.9269x; 1.2168x over previous
//
#include <hip/hip_runtime.h>

#define GYD 512
#define GXD 512
#define HD 256
#define WD 256
#define BD 8
#define NSAMP 100000
#define JD 7
#define NC 8            // columns per col-FFT tile
#define NCP 9           // padded LDS stride

__device__ __forceinline__ int brev9(int i) {
    return (int)(__brev((unsigned)i) >> 23);
}

// In-LDS 512-point radix-2 DIT FFT (input already stored bit-reversed).
__device__ __forceinline__ void fft512(float* re, float* im, int t) {
    #pragma unroll
    for (int s = 1; s <= 9; ++s) {
        const int len = 1 << s;
        const int half = len >> 1;
        const int off = t & (half - 1);
        const int blk = t >> (s - 1);
        const int p = blk * len + off;
        const int q = p + half;
        float sn, cs;
        sincospif(-2.0f * (float)off / (float)len, &sn, &cs);
        __syncthreads();
        const float ur = re[p], ui = im[p];
        const float ar = re[q], ai = im[q];
        const float vr = ar * cs - ai * sn;
        const float vi = ar * sn + ai * cs;
        re[p] = ur + vr; im[p] = ui + vi;
        re[q] = ur - vr; im[q] = ui - vi;
    }
    __syncthreads();
}

// Kernel A: apodization + zero-padded row FFT. One block per (b, y).
__global__ __launch_bounds__(256) void rowfft_kernel(
    const float* __restrict__ xr, const float* __restrict__ xi,
    const float* __restrict__ sc_y, const float* __restrict__ sc_x,
    float2* __restrict__ G1)
{
    __shared__ float re[512];
    __shared__ float im[512];
    const int t = threadIdx.x;
    const int by = blockIdx.x;       // b*256 + y
    const int b = by >> 8;
    const int y = by & 255;
    const float s = sc_y[y] * sc_x[t];
    const int base = b * (HD * WD) + y * WD;
    const float vr = xr[base + t] * s;
    const float vi = xi[base + t] * s;
    const int p0 = brev9(t);
    re[p0] = vr; im[p0] = vi;
    const int p1 = brev9(t + 256);   // zero-padded half
    re[p1] = 0.0f; im[p1] = 0.0f;
    fft512(re, im, t);
    float2* out = G1 + (size_t)b * (HD * GXD) + (size_t)y * GXD;
    out[t]       = make_float2(re[t],       im[t]);
    out[t + 256] = make_float2(re[t + 256], im[t + 256]);
}

// Kernel B: LDS-tiled zero-padded column FFT + ortho scale.
// One block per (b, 8-column tile): grid = 8 * 64 = 512 blocks.
// Writes batch-INTERLEAVED layout: ghat2[(y*512 + x)*8 + b].
__global__ __launch_bounds__(256) void colfft_kernel(
    const float2* __restrict__ G1, float2* __restrict__ ghat2)
{
    __shared__ float re[512 * NCP];
    __shared__ float im[512 * NCP];
    __shared__ float tw_re[256];
    __shared__ float tw_im[256];
    const int t = threadIdx.x;
    const int blk = blockIdx.x;           // b + 8*tile
    const int b = blk & 7;
    const int kx0 = (blk >> 3) * NC;

    // twiddle table: tw[m] = exp(-2*pi*i*m/512), m = 0..255
    {
        float sn, cs;
        sincospif(-(float)t / 256.0f, &sn, &cs);
        tw_re[t] = cs; tw_im[t] = sn;
    }

    // Load valid rows 0..255 bit-reversed; zero rows 256..511.
    const float2* src = G1 + (size_t)b * (HD * GXD) + kx0;
    for (int i = t; i < 256 * NC; i += 256) {
        const int y = i >> 3;
        const int c = i & 7;
        const float2 v = src[(size_t)y * GXD + c];
        const int p = brev9(y);
        re[p * NCP + c] = v.x;
        im[p * NCP + c] = v.y;
        const int p2 = brev9(y + 256);
        re[p2 * NCP + c] = 0.0f;
        im[p2 * NCP + c] = 0.0f;
    }
    __syncthreads();

    // 8 FFTs of length 512. Thread t: column c = t&7, tt = t>>3 (0..31).
    const int c = t & 7;
    const int tt = t >> 3;
    #pragma unroll
    for (int s = 1; s <= 9; ++s) {
        const int len = 1 << s;
        const int half = len >> 1;
        const int sh = 9 - s;
        #pragma unroll
        for (int k = 0; k < 8; ++k) {
            const int m = tt * 8 + k;            // butterfly index 0..255
            const int off = m & (half - 1);
            const int bi = m >> (s - 1);
            const int p = (bi * len + off) * NCP + c;
            const int q = p + half * NCP;
            const float cs = tw_re[off << sh];
            const float sn = tw_im[off << sh];
            const float ur = re[p], ui = im[p];
            const float ar = re[q], ai = im[q];
            const float vr = ar * cs - ai * sn;
            const float vi = ar * sn + ai * cs;
            re[p] = ur + vr; im[p] = ui + vi;
            re[q] = ur - vr; im[q] = ui - vi;
        }
        __syncthreads();
    }

    // Write-back with ortho scale into interleaved layout.
    const float scale = 1.0f / 512.0f;   // 1/sqrt(512*512)
    for (int i = t; i < 512 * NC; i += 256) {
        const int y = i >> 3;
        const int cc = i & 7;
        ghat2[((size_t)y * GXD + kx0 + cc) * BD + b] =
            make_float2(re[y * NCP + cc] * scale, im[y * NCP + cc] * scale);
    }
}

// Kernel C: 7x7 KB gather on interleaved ghat2.
// Wave = 8 samples x 8 batches; the 8 b-lanes of a sample read 64 contiguous
// bytes per tap -> 1 coalesced transaction instead of 8.
__global__ __launch_bounds__(256) void gather_kernel(
    const float2* __restrict__ ghat2,
    const float* __restrict__ wy, const float* __restrict__ wx,
    const float* __restrict__ phr, const float* __restrict__ phi,
    const int* __restrict__ iy, const int* __restrict__ ix,
    float2* __restrict__ out)
{
    const int b = threadIdx.x & 7;
    const int n = blockIdx.x * 32 + (threadIdx.x >> 3);   // 3125*32 = 100000 exact

    int iyl[JD], ixl[JD];
    float wyl[JD], wxl[JD];
    #pragma unroll
    for (int j = 0; j < JD; ++j) {
        iyl[j] = iy[n * JD + j];
        ixl[j] = ix[n * JD + j];
        wyl[j] = wy[n * JD + j];
        wxl[j] = wx[n * JD + j];
    }

    float ar = 0.0f, ai = 0.0f;
    #pragma unroll
    for (int j = 0; j < JD; ++j) {
        const int rowoff = iyl[j] * GXD;
        const float wj = wyl[j];
        #pragma unroll
        for (int k = 0; k < JD; ++k) {
            const float w = wj * wxl[k];
            const float2 v = ghat2[(size_t)(rowoff + ixl[k]) * BD + b];
            ar += v.x * w;
            ai += v.y * w;
        }
    }

    const float pr = phr[n], pi = phi[n];
    out[(size_t)b * NSAMP + n] = make_float2(ar * pr - ai * pi,
                                             ar * pi + ai * pr);
}

extern "C" void kernel_launch(void* const* d_in, const int* in_sizes, int n_in,
                              void* d_out, int out_size, void* d_ws, size_t ws_size,
                              hipStream_t stream) {
    const float* xr   = (const float*)d_in[0];
    const float* xi   = (const float*)d_in[1];
    const float* sc_y = (const float*)d_in[2];
    const float* sc_x = (const float*)d_in[3];
    const float* wy   = (const float*)d_in[4];
    const float* wx   = (const float*)d_in[5];
    const float* phr  = (const float*)d_in[6];
    const float* phi  = (const float*)d_in[7];
    const int*   iy   = (const int*)d_in[8];
    const int*   ix   = (const int*)d_in[9];

    // Workspace layout: G1 (8 MB, planar) | ghat2 (16 MB, batch-interleaved)
    float2* G1    = (float2*)d_ws;
    float2* ghat2 = (float2*)((char*)d_ws + (size_t)BD * HD * GXD * sizeof(float2));

    rowfft_kernel<<<BD * HD, 256, 0, stream>>>(xr, xi, sc_y, sc_x, G1);
    colfft_kernel<<<BD * (GXD / NC), 256, 0, stream>>>(G1, ghat2);
    gather_kernel<<<NSAMP / 32, 256, 0, stream>>>(
        ghat2, wy, wx, phr, phi, iy, ix, (float2*)d_out);
}

// Round 4
// 147.316 us; speedup vs baseline: 2.1765x; 1.1296x over previous
//
#include <hip/hip_runtime.h>

#define GYD 512
#define GXD 512
#define HD 256
#define WD 256
#define BD 8
#define NSAMP 100000
#define JD 7
#define NCP 9           // padded LDS stride (8 columns + 1)

__device__ __forceinline__ int brev9(int i) {
    return (int)(__brev((unsigned)i) >> 23);
}

// Shared FFT core: 8 independent 512-pt radix-2 DIT FFTs in LDS.
// Data at re/im[point*NCP + col], input pre-stored bit-reversed.
// 256 threads: col c = t&7, tt = t>>3; per stage each thread does 8 butterflies.
__device__ __forceinline__ void fft512x8(float* re, float* im,
                                         const float* tw_re, const float* tw_im,
                                         int t) {
    const int c = t & 7;
    const int tt = t >> 3;
    #pragma unroll
    for (int s = 1; s <= 9; ++s) {
        const int len = 1 << s;
        const int half = len >> 1;
        const int sh = 9 - s;
        #pragma unroll
        for (int k = 0; k < 8; ++k) {
            const int m = tt * 8 + k;            // butterfly index 0..255
            const int off = m & (half - 1);
            const int bi = m >> (s - 1);
            const int p = (bi * len + off) * NCP + c;
            const int q = p + half * NCP;
            const float cs = tw_re[off << sh];
            const float sn = tw_im[off << sh];
            const float ur = re[p], ui = im[p];
            const float ar = re[q], ai = im[q];
            const float vr = ar * cs - ai * sn;
            const float vi = ar * sn + ai * cs;
            re[p] = ur + vr; im[p] = ui + vi;
            re[q] = ur - vr; im[q] = ui - vi;
        }
        __syncthreads();
    }
}

// Kernel A: apodized zero-padded row FFT for ALL 8 batches of one y row.
// Grid = 256 blocks. Writes batch-interleaved G1i[(y*512+x)*8 + b],
// which is contiguous in (x,b) -> fully coalesced float4 stores.
__global__ __launch_bounds__(256) void rowfft_kernel(
    const float* __restrict__ xr, const float* __restrict__ xi,
    const float* __restrict__ sc_y, const float* __restrict__ sc_x,
    float4* __restrict__ G1i)
{
    __shared__ float re[512 * NCP];
    __shared__ float im[512 * NCP];
    __shared__ float tw_re[256];
    __shared__ float tw_im[256];
    const int t = threadIdx.x;
    const int y = blockIdx.x;

    {   // twiddle table: tw[m] = exp(-i*pi*m/256)
        float sn, cs;
        sincospif(-(float)t / 256.0f, &sn, &cs);
        tw_re[t] = cs; tw_im[t] = sn;
    }

    // Load row y of all 8 batches, apodize, store bit-reversed; column = batch.
    const float syv = sc_y[y];
    const float s = syv * sc_x[t];
    const int p0 = brev9(t) * NCP;
    const int p1 = brev9(t + 256) * NCP;
    #pragma unroll
    for (int b = 0; b < BD; ++b) {
        const int base = b * (HD * WD) + y * WD + t;
        re[p0 + b] = xr[base] * s;
        im[p0 + b] = xi[base] * s;
        re[p1 + b] = 0.0f;              // x zero-pad 256..511
        im[p1 + b] = 0.0f;
    }
    __syncthreads();

    fft512x8(re, im, tw_re, tw_im, t);

    // Contiguous write: float2 index y*4096 + i, i = x*8+b. Pair i, i+1 -> float4.
    float4* dst = G1i + (size_t)y * 2048;        // 4096 float2 = 2048 float4
    #pragma unroll
    for (int iter = 0; iter < 8; ++iter) {
        const int i = iter * 512 + t * 2;        // even
        const int x = i >> 3;
        const int b = i & 7;
        const int a0 = x * NCP + b;
        dst[i >> 1] = make_float4(re[a0], im[a0], re[a0 + 1], im[a0 + 1]);
    }
}

// Kernel B: zero-padded column FFT for ALL 8 batches of one x column.
// Grid = 512 blocks. Reads/writes interleaved layout: per y, the 8 batches
// are one fully-consumed 64 B line (float4, 2 batches per lane).
__global__ __launch_bounds__(256) void colfft_kernel(
    const float4* __restrict__ G1i, float4* __restrict__ ghat2)
{
    __shared__ float re[512 * NCP];
    __shared__ float im[512 * NCP];
    __shared__ float tw_re[256];
    __shared__ float tw_im[256];
    const int t = threadIdx.x;
    const int x = blockIdx.x;

    {
        float sn, cs;
        sincospif(-(float)t / 256.0f, &sn, &cs);
        tw_re[t] = cs; tw_im[t] = sn;
    }

    // Load y = 0..255 (valid rows), 2 batches per lane via float4.
    const int b2 = t & 3;            // batch pair: b = 2*b2, 2*b2+1
    const int yy = t >> 2;           // 0..63
    #pragma unroll
    for (int iter = 0; iter < 4; ++iter) {
        const int y = iter * 64 + yy;
        const float4 v = G1i[((size_t)y * GXD + x) * 4 + b2];
        const int p = brev9(y) * NCP + b2 * 2;
        re[p]     = v.x; im[p]     = v.y;
        re[p + 1] = v.z; im[p + 1] = v.w;
    }
    // Zero rows 256..511 (y zero-pad).
    for (int i = t; i < 256 * BD; i += 256) {
        const int y = 256 + (i >> 3);
        const int c = i & 7;
        const int p = brev9(y) * NCP + c;
        re[p] = 0.0f; im[p] = 0.0f;
    }
    __syncthreads();

    fft512x8(re, im, tw_re, tw_im, t);

    // Write with ortho scale; same fully-consumed-line pattern.
    const float scale = 1.0f / 512.0f;   // 1/sqrt(512*512)
    #pragma unroll
    for (int iter = 0; iter < 8; ++iter) {
        const int y = iter * 64 + yy;
        const int p = y * NCP + b2 * 2;
        ghat2[((size_t)y * GXD + x) * 4 + b2] =
            make_float4(re[p] * scale, im[p] * scale,
                        re[p + 1] * scale, im[p + 1] * scale);
    }
}

// Kernel C: 7x7 KB gather on interleaved ghat2.
// Wave = 8 samples x 8 batches; the 8 b-lanes of a sample read 64 contiguous
// bytes per tap -> 1 coalesced transaction per sample-tap.
__global__ __launch_bounds__(256) void gather_kernel(
    const float2* __restrict__ ghat2,
    const float* __restrict__ wy, const float* __restrict__ wx,
    const float* __restrict__ phr, const float* __restrict__ phi,
    const int* __restrict__ iy, const int* __restrict__ ix,
    float2* __restrict__ out)
{
    const int b = threadIdx.x & 7;
    const int n = blockIdx.x * 32 + (threadIdx.x >> 3);   // 3125*32 = 100000 exact

    int iyl[JD], ixl[JD];
    float wyl[JD], wxl[JD];
    #pragma unroll
    for (int j = 0; j < JD; ++j) {
        iyl[j] = iy[n * JD + j];
        ixl[j] = ix[n * JD + j];
        wyl[j] = wy[n * JD + j];
        wxl[j] = wx[n * JD + j];
    }

    float ar = 0.0f, ai = 0.0f;
    #pragma unroll
    for (int j = 0; j < JD; ++j) {
        const int rowoff = iyl[j] * GXD;
        const float wj = wyl[j];
        #pragma unroll
        for (int k = 0; k < JD; ++k) {
            const float w = wj * wxl[k];
            const float2 v = ghat2[(size_t)(rowoff + ixl[k]) * BD + b];
            ar += v.x * w;
            ai += v.y * w;
        }
    }

    const float pr = phr[n], pi = phi[n];
    out[(size_t)b * NSAMP + n] = make_float2(ar * pr - ai * pi,
                                             ar * pi + ai * pr);
}

extern "C" void kernel_launch(void* const* d_in, const int* in_sizes, int n_in,
                              void* d_out, int out_size, void* d_ws, size_t ws_size,
                              hipStream_t stream) {
    const float* xr   = (const float*)d_in[0];
    const float* xi   = (const float*)d_in[1];
    const float* sc_y = (const float*)d_in[2];
    const float* sc_x = (const float*)d_in[3];
    const float* wy   = (const float*)d_in[4];
    const float* wx   = (const float*)d_in[5];
    const float* phr  = (const float*)d_in[6];
    const float* phi  = (const float*)d_in[7];
    const int*   iy   = (const int*)d_in[8];
    const int*   ix   = (const int*)d_in[9];

    // Workspace: G1i (8.4 MB, interleaved [y][x*8+b]) | ghat2 (16.8 MB, interleaved)
    float4* G1i   = (float4*)d_ws;
    float4* ghat2 = (float4*)((char*)d_ws + (size_t)HD * GXD * BD * sizeof(float2));

    rowfft_kernel<<<HD, 256, 0, stream>>>(xr, xi, sc_y, sc_x, G1i);
    colfft_kernel<<<GXD, 256, 0, stream>>>(G1i, ghat2);
    gather_kernel<<<NSAMP / 32, 256, 0, stream>>>(
        (const float2*)ghat2, wy, wx, phr, phi, iy, ix, (float2*)d_out);
}

// Round 5
// 133.506 us; speedup vs baseline: 2.4017x; 1.1034x over previous
//
#include <hip/hip_runtime.h>

#define GYD 512
#define GXD 512
#define HD 256
#define WD 256
#define BD 8
#define NSAMP 100000
#define JD 7
#define NCP 9           // padded LDS stride (8 batch columns + 1)

// digit-reverse base 8, 3 digits (involution)
__device__ __forceinline__ int dr3(int i) {
    return ((i & 7) << 6) | (i & 56) | ((i >> 6) & 7);
}

// One radix-8 DIT stage over 8 interleaved 512-pt FFTs in LDS.
// g = global butterfly id (0..511): c = g&7 (FFT column), m = g>>3 (butterfly).
// TWSH = log2(512/LEN)... twiddle idx = off*j*(512/LEN) = (off*j)<<TWSH; -1 = no twiddle.
template<int LEN, int EIGHTH, int TWSH>
__device__ __forceinline__ void r8_stage(float* __restrict__ re, float* __restrict__ im,
                                         const float* __restrict__ twr,
                                         const float* __restrict__ twi, int g) {
    const int c = g & 7;
    const int m = g >> 3;
    const int off = m & (EIGHTH - 1);
    const int blk = m / EIGHTH;
    const int p0 = (blk * LEN + off) * NCP + c;
    float ar[8], ai[8];
    #pragma unroll
    for (int j = 0; j < 8; ++j) {
        ar[j] = re[p0 + j * EIGHTH * NCP];
        ai[j] = im[p0 + j * EIGHTH * NCP];
    }
    if (TWSH >= 0) {
        #pragma unroll
        for (int j = 1; j < 8; ++j) {
            const int idx = (off * j) << (TWSH >= 0 ? TWSH : 0);
            const float cr = twr[idx], ci = twi[idx];
            const float tr = ar[j] * cr - ai[j] * ci;
            ai[j] = ar[j] * ci + ai[j] * cr;
            ar[j] = tr;
        }
    }
    // 8-point DFT over j. Evens (0,2,4,6) -> E, odds (1,3,5,7) -> O.
    const float e0r = ar[0] + ar[4], e0i = ai[0] + ai[4];
    const float e1r = ar[0] - ar[4], e1i = ai[0] - ai[4];
    const float e2r = ar[2] + ar[6], e2i = ai[2] + ai[6];
    const float e3r = ar[2] - ar[6], e3i = ai[2] - ai[6];
    const float E0r = e0r + e2r, E0i = e0i + e2i;
    const float E2r = e0r - e2r, E2i = e0i - e2i;
    const float E1r = e1r + e3i, E1i = e1i - e3r;   // e1 - i*e3
    const float E3r = e1r - e3i, E3i = e1i + e3r;   // e1 + i*e3

    const float q0r = ar[1] + ar[5], q0i = ai[1] + ai[5];
    const float q1r = ar[1] - ar[5], q1i = ai[1] - ai[5];
    const float q2r = ar[3] + ar[7], q2i = ai[3] + ai[7];
    const float q3r = ar[3] - ar[7], q3i = ai[3] - ai[7];
    const float O0r = q0r + q2r, O0i = q0i + q2i;
    const float O2r = q0r - q2r, O2i = q0i - q2i;
    const float O1r = q1r + q3i, O1i = q1i - q3r;
    const float O3r = q1r - q3i, O3i = q1i + q3r;

    const float S = 0.70710678118654752f;
    // T_k = W8^k * O_k
    const float T0r = O0r,              T0i = O0i;
    const float T1r = S * (O1r + O1i),  T1i = S * (O1i - O1r);
    const float T2r = O2i,              T2i = -O2r;
    const float T3r = S * (O3i - O3r),  T3i = -S * (O3r + O3i);

    re[p0 + 0 * EIGHTH * NCP] = E0r + T0r;  im[p0 + 0 * EIGHTH * NCP] = E0i + T0i;
    re[p0 + 4 * EIGHTH * NCP] = E0r - T0r;  im[p0 + 4 * EIGHTH * NCP] = E0i - T0i;
    re[p0 + 1 * EIGHTH * NCP] = E1r + T1r;  im[p0 + 1 * EIGHTH * NCP] = E1i + T1i;
    re[p0 + 5 * EIGHTH * NCP] = E1r - T1r;  im[p0 + 5 * EIGHTH * NCP] = E1i - T1i;
    re[p0 + 2 * EIGHTH * NCP] = E2r + T2r;  im[p0 + 2 * EIGHTH * NCP] = E2i + T2i;
    re[p0 + 6 * EIGHTH * NCP] = E2r - T2r;  im[p0 + 6 * EIGHTH * NCP] = E2i - T2i;
    re[p0 + 3 * EIGHTH * NCP] = E3r + T3r;  im[p0 + 3 * EIGHTH * NCP] = E3i + T3i;
    re[p0 + 7 * EIGHTH * NCP] = E3r - T3r;  im[p0 + 7 * EIGHTH * NCP] = E3i - T3i;
}

// Kernel A: apodized zero-padded row FFT for ALL 8 batches of one y row.
// 512 threads, grid = 256. Output batch-interleaved G1i[(y*512+x)*8+b],
// contiguous in (x,b) -> fully coalesced float4 stores.
__global__ __launch_bounds__(512) void rowfft_kernel(
    const float* __restrict__ xr, const float* __restrict__ xi,
    const float* __restrict__ sc_y, const float* __restrict__ sc_x,
    float4* __restrict__ G1i4)
{
    __shared__ float re[512 * NCP];
    __shared__ float im[512 * NCP];
    __shared__ float twr[512];
    __shared__ float twi[512];
    const int t = threadIdx.x;
    const int y = blockIdx.x;

    {   // tw[m] = exp(-2*pi*i*m/512)
        float sn, cs;
        sincospif(-(float)t / 256.0f, &sn, &cs);
        twr[t] = cs; twi[t] = sn;
    }

    const float sy = sc_y[y];
    {
        const int b = t >> 6;               // 0..7
        const int x4 = (t & 63) << 2;       // 0..252 step 4
        const float4 vr = *(const float4*)(xr + b * (HD * WD) + y * WD + x4);
        const float4 vi = *(const float4*)(xi + b * (HD * WD) + y * WD + x4);
        const float4 sx = *(const float4*)(sc_x + x4);
        int p;
        float s;
        s = sy * sx.x; p = dr3(x4 + 0) * NCP + b; re[p] = vr.x * s; im[p] = vi.x * s;
        s = sy * sx.y; p = dr3(x4 + 1) * NCP + b; re[p] = vr.y * s; im[p] = vi.y * s;
        s = sy * sx.z; p = dr3(x4 + 2) * NCP + b; re[p] = vr.z * s; im[p] = vi.z * s;
        s = sy * sx.w; p = dr3(x4 + 3) * NCP + b; re[p] = vr.w * s; im[p] = vi.w * s;
        #pragma unroll
        for (int k = 0; k < 4; ++k) {       // x zero-pad 256..511
            p = dr3(x4 + 256 + k) * NCP + b;
            re[p] = 0.0f; im[p] = 0.0f;
        }
    }
    __syncthreads();
    r8_stage<8, 1, -1>(re, im, twr, twi, t);
    __syncthreads();
    r8_stage<64, 8, 3>(re, im, twr, twi, t);
    __syncthreads();
    r8_stage<512, 64, 0>(re, im, twr, twi, t);
    __syncthreads();

    float4* dst = G1i4 + (size_t)y * 2048;   // 4096 float2 = 2048 float4 per row
    #pragma unroll
    for (int iter = 0; iter < 4; ++iter) {
        const int if4 = iter * 512 + t;      // 0..2047
        const int x = if4 >> 2;
        const int b = (if4 & 3) << 1;
        const int p = x * NCP + b;
        dst[if4] = make_float4(re[p], im[p], re[p + 1], im[p + 1]);
    }
}

// Kernel B: zero-padded column FFT for ALL 8 batches of one x column.
// 512 threads, grid = 512. Interleaved reads/writes are fully-consumed lines.
__global__ __launch_bounds__(512) void colfft_kernel(
    const float4* __restrict__ G1i4, float4* __restrict__ ghat4)
{
    __shared__ float re[512 * NCP];
    __shared__ float im[512 * NCP];
    __shared__ float twr[512];
    __shared__ float twi[512];
    const int t = threadIdx.x;
    const int x = blockIdx.x;

    {
        float sn, cs;
        sincospif(-(float)t / 256.0f, &sn, &cs);
        twr[t] = cs; twi[t] = sn;
    }

    #pragma unroll
    for (int iter = 0; iter < 2; ++iter) {
        const int i = iter * 512 + t;        // 0..1023
        const int yy = i >> 2;               // 0..255
        const int bp = (i & 3) << 1;
        const float4 v = G1i4[((size_t)yy * GXD + x) * 4 + (i & 3)];
        const int p = dr3(yy) * NCP + bp;
        re[p] = v.x; im[p] = v.y; re[p + 1] = v.z; im[p + 1] = v.w;
        const int p2 = dr3(yy + 256) * NCP + bp;   // y zero-pad
        re[p2] = 0.0f; im[p2] = 0.0f; re[p2 + 1] = 0.0f; im[p2 + 1] = 0.0f;
    }
    __syncthreads();
    r8_stage<8, 1, -1>(re, im, twr, twi, t);
    __syncthreads();
    r8_stage<64, 8, 3>(re, im, twr, twi, t);
    __syncthreads();
    r8_stage<512, 64, 0>(re, im, twr, twi, t);
    __syncthreads();

    const float scale = 1.0f / 512.0f;       // ortho: 1/sqrt(512*512)
    #pragma unroll
    for (int iter = 0; iter < 4; ++iter) {
        const int if4 = iter * 512 + t;      // 0..2047
        const int yy = if4 >> 2;             // 0..511
        const int b = (if4 & 3) << 1;
        const int p = yy * NCP + b;
        ghat4[((size_t)yy * GXD + x) * 4 + (if4 & 3)] =
            make_float4(re[p] * scale, im[p] * scale,
                        re[p + 1] * scale, im[p + 1] * scale);
    }
}

// Kernel C: 7x7 KB gather on interleaved ghat2. Block = 32 samples x 8 batches.
// Per-sample indices/weights staged once into LDS (coalesced), then broadcast.
__global__ __launch_bounds__(256) void gather_kernel(
    const float2* __restrict__ ghat2,
    const float* __restrict__ wy, const float* __restrict__ wx,
    const float* __restrict__ phr, const float* __restrict__ phi,
    const int* __restrict__ iy, const int* __restrict__ ix,
    float2* __restrict__ out)
{
    __shared__ int s_iy[32 * JD];
    __shared__ int s_ix[32 * JD];
    __shared__ float s_wy[32 * JD];
    __shared__ float s_wx[32 * JD];
    __shared__ float s_pr[32];
    __shared__ float s_pi[32];
    const int t = threadIdx.x;
    const int n0 = blockIdx.x * 32;

    if (t < 32 * JD) {
        const int g = n0 * JD + t;
        s_iy[t] = iy[g];
        s_ix[t] = ix[g];
        s_wy[t] = wy[g];
        s_wx[t] = wx[g];
    }
    if (t < 32) { s_pr[t] = phr[n0 + t]; s_pi[t] = phi[n0 + t]; }
    __syncthreads();

    const int b = t & 7;
    const int s = t >> 3;                    // sample within block, 0..31
    const int base = s * JD;

    int iyl[JD], ixl[JD];
    float wyl[JD], wxl[JD];
    #pragma unroll
    for (int j = 0; j < JD; ++j) {
        iyl[j] = s_iy[base + j];
        ixl[j] = s_ix[base + j];
        wyl[j] = s_wy[base + j];
        wxl[j] = s_wx[base + j];
    }

    float ar = 0.0f, ai = 0.0f;
    #pragma unroll
    for (int j = 0; j < JD; ++j) {
        const int rowoff = iyl[j] * GXD;
        const float wj = wyl[j];
        #pragma unroll
        for (int k = 0; k < JD; ++k) {
            const float w = wj * wxl[k];
            const float2 v = ghat2[(size_t)(rowoff + ixl[k]) * BD + b];
            ar += v.x * w;
            ai += v.y * w;
        }
    }

    const int n = n0 + s;
    const float pr = s_pr[s], pi = s_pi[s];
    out[(size_t)b * NSAMP + n] = make_float2(ar * pr - ai * pi,
                                             ar * pi + ai * pr);
}

extern "C" void kernel_launch(void* const* d_in, const int* in_sizes, int n_in,
                              void* d_out, int out_size, void* d_ws, size_t ws_size,
                              hipStream_t stream) {
    const float* xr   = (const float*)d_in[0];
    const float* xi   = (const float*)d_in[1];
    const float* sc_y = (const float*)d_in[2];
    const float* sc_x = (const float*)d_in[3];
    const float* wy   = (const float*)d_in[4];
    const float* wx   = (const float*)d_in[5];
    const float* phr  = (const float*)d_in[6];
    const float* phi  = (const float*)d_in[7];
    const int*   iy   = (const int*)d_in[8];
    const int*   ix   = (const int*)d_in[9];

    // Workspace: G1i (8.4 MB, interleaved [y][x*8+b]) | ghat2 (16.8 MB, interleaved)
    float4* G1i4  = (float4*)d_ws;
    float4* ghat4 = (float4*)((char*)d_ws + (size_t)HD * GXD * BD * sizeof(float2));

    rowfft_kernel<<<HD, 512, 0, stream>>>(xr, xi, sc_y, sc_x, G1i4);
    colfft_kernel<<<GXD, 512, 0, stream>>>(G1i4, ghat4);
    gather_kernel<<<NSAMP / 32, 256, 0, stream>>>(
        (const float2*)ghat4, wy, wx, phr, phi, iy, ix, (float2*)d_out);
}